// Round 1
// baseline (24112.498 us; speedup 1.0000x reference)
//
#include <hip/hip_runtime.h>

#define HID   256
#define NDEG  9           // degree+1 coefficients
#define PTS   64          // points per block
#define NTH   256

// transposed-weight offsets (in floats) inside d_ws; layout [i][d][o]
#define OFF0  0
#define SZ0   (3*NDEG*HID)            // 6912
#define OFF1  SZ0
#define SZH   (HID*NDEG*HID)          // 589824 per middle layer
#define OFF7  (OFF1 + 6*SZH)
#define SZ7   (HID*NDEG*1)            // 2304

// ---------------- weight transpose: w[i][o][d] -> wt[i][d][o] ----------------
__global__ void transpose_w(const float* __restrict__ src, float* __restrict__ dst,
                            int in_dim, int out_dim) {
    int idx = blockIdx.x * blockDim.x + threadIdx.x;
    int total = in_dim * out_dim * NDEG;
    if (idx >= total) return;
    int i = idx / (out_dim * NDEG);
    int r = idx - i * (out_dim * NDEG);
    int o = r / NDEG;
    int d = r - o * NDEG;
    dst[(i * NDEG + d) * out_dim + o] = src[idx];   // read coalesced, write scattered
}

// ---------------- device helpers ----------------
__device__ __forceinline__ void cheb_store(float* p, float x) {
    // writes T_0..T_8(x) at stride PTS floats
    float t0 = 1.0f, t1 = x;
    p[0]   = t0;
    p[PTS] = t1;
#pragma unroll
    for (int d = 2; d < NDEG; d++) {
        float t2 = 2.0f * x * t1 - t0;
        p[d * PTS] = t2;
        t0 = t1; t1 = t2;
    }
}

template <int J0>
__device__ __forceinline__ void fma_block(float (&acc)[16][4], const float4& a, const float4& b) {
#define ROW(JJ, BV)                                  \
    acc[JJ][0] = fmaf(BV, a.x, acc[JJ][0]);          \
    acc[JJ][1] = fmaf(BV, a.y, acc[JJ][1]);          \
    acc[JJ][2] = fmaf(BV, a.z, acc[JJ][2]);          \
    acc[JJ][3] = fmaf(BV, a.w, acc[JJ][3]);
    ROW(J0 + 0, b.x)
    ROW(J0 + 1, b.y)
    ROW(J0 + 2, b.z)
    ROW(J0 + 3, b.w)
#undef ROW
}

template <int K>
__device__ __forceinline__ void kloop(const float* __restrict__ wk, const float* tbp,
                                      int pgrp, int ogrp, float (&acc)[16][4]) {
#pragma unroll 3
    for (int k = 0; k < K; k++) {
        // A-frag: 4 points of T-basis row k (LDS, 16B aligned, broadcast across o-groups)
        float4 a = *reinterpret_cast<const float4*>(tbp + k * PTS + pgrp * 4);
        // B-frag: 16 outputs of weight row k (global, L2-hot, coalesced)
        const float4* w4 = reinterpret_cast<const float4*>(wk + k * HID + ogrp * 16);
        float4 b0 = w4[0];
        float4 b1 = w4[1];
        float4 b2 = w4[2];
        float4 b3 = w4[3];
        fma_block<0>(acc, a, b0);
        fma_block<4>(acc, a, b1);
        fma_block<8>(acc, a, b2);
        fma_block<12>(acc, a, b3);
    }
}

__device__ __forceinline__ void zero_acc(float (&acc)[16][4]) {
#pragma unroll
    for (int j = 0; j < 16; j++)
#pragma unroll
        for (int q = 0; q < 4; q++) acc[j][q] = 0.0f;
}

__device__ __forceinline__ void writeback(float* h, float (&acc)[16][4], int ogrp, int pgrp) {
#pragma unroll
    for (int j = 0; j < 16; j++) {
        *reinterpret_cast<float4*>(&h[(ogrp * 16 + j) * PTS + pgrp * 4]) =
            make_float4(acc[j][0], acc[j][1], acc[j][2], acc[j][3]);
    }
}

// ---------------- fused network kernel ----------------
// block = 64 points x full 256-wide hidden; h kept in LDS layout [ch][pt]
__global__ __launch_bounds__(NTH, 2)
void kan_fused(const float* __restrict__ nonm, const float* __restrict__ mnf,
               const float* __restrict__ wt, float* __restrict__ out) {
    __shared__ __align__(16) float h[HID * PTS];      // 64 KB  activations [ch][pt]
    __shared__ __align__(16) float tb[4 * NDEG * PTS]; // 9 KB  T-basis chunk [k][pt]

    const int t = threadIdx.x;
    const int b = blockIdx.x;
    // output order: mnfld_pred (blocks 0..1023), nonmnfld_pred (blocks 1024..2047)
    const float* src = (b < 1024) ? mnf : nonm;
    const int pb = (b < 1024) ? b * PTS : (b - 1024) * PTS;

    // load 64 points x 3 coords into h[ch][pt]
    if (t < 192) {
        float v = src[pb * 3 + t];
        h[(t % 3) * PTS + (t / 3)] = v;
    }
    __syncthreads();

    const int ogrp = t & 15;   // thread covers outs  ogrp*16 .. +15
    const int pgrp = t >> 4;   // thread covers points pgrp*4 .. +3
    const int tp  = t & 63;    // T-step: point
    const int til = t >> 6;    // T-step: channel-within-chunk (0..3)

    float acc[16][4];

    // ---- layer 0: 3 -> 256, K = 27 ----
    zero_acc(acc);
    if (til < 3) cheb_store(&tb[(til * NDEG) * PTS + tp], tanhf(h[til * PTS + tp]));
    __syncthreads();
    kloop<27>(wt + OFF0, tb, pgrp, ogrp, acc);
    __syncthreads();
    writeback(h, acc, ogrp, pgrp);
    __syncthreads();

    // ---- layers 1..6: 256 -> 256, K = 2304 in chunks of 36 (4 channels) ----
    for (int L = 0; L < 6; L++) {
        const float* wL = wt + OFF1 + L * SZH;
        zero_acc(acc);
        for (int c = 0; c < 64; c++) {
            cheb_store(&tb[(til * NDEG) * PTS + tp], tanhf(h[(c * 4 + til) * PTS + tp]));
            __syncthreads();
            kloop<36>(wL + c * 36 * HID, tb, pgrp, ogrp, acc);
            __syncthreads();
        }
        writeback(h, acc, ogrp, pgrp);
        __syncthreads();
    }

    // ---- layer 7: 256 -> 1 ----
    {
        const float* w7 = wt + OFF7;
        const int p = tp, seg = til;  // 4 threads per point, 64 channels each
        float s = 0.0f;
        for (int i = seg * 64; i < seg * 64 + 64; i++) {
            float x = tanhf(h[i * PTS + p]);
            const float* wr = &w7[i * NDEG];
            float t0 = 1.0f, t1 = x;
            s = fmaf(wr[0], t0, s);
            s = fmaf(wr[1], t1, s);
#pragma unroll
            for (int d = 2; d < NDEG; d++) {
                float t2 = 2.0f * x * t1 - t0;
                s = fmaf(wr[d], t2, s);
                t0 = t1; t1 = t2;
            }
        }
        tb[seg * PTS + p] = s;   // tb free here (all kloop reads done before last sync)
        __syncthreads();
        if (t < PTS) {
            out[b * PTS + t] = tb[t] + tb[PTS + t] + tb[2 * PTS + t] + tb[3 * PTS + t];
        }
    }
}

// ---------------- launch ----------------
extern "C" void kernel_launch(void* const* d_in, const int* in_sizes, int n_in,
                              void* d_out, int out_size, void* d_ws, size_t ws_size,
                              hipStream_t stream) {
    const float* nonm = (const float*)d_in[0];
    const float* mnf  = (const float*)d_in[1];
    float* ws = (float*)d_ws;

    // transpose all weights into d_ws (re-done every call; d_ws is re-poisoned)
    {
        int total = 3 * HID * NDEG;
        transpose_w<<<(total + 255) / 256, 256, 0, stream>>>((const float*)d_in[2], ws + OFF0, 3, HID);
    }
    for (int L = 0; L < 6; L++) {
        int total = HID * HID * NDEG;
        transpose_w<<<(total + 255) / 256, 256, 0, stream>>>((const float*)d_in[3 + L], ws + OFF1 + L * SZH, HID, HID);
    }
    {
        int total = HID * NDEG;
        transpose_w<<<(total + 255) / 256, 256, 0, stream>>>((const float*)d_in[9], ws + OFF7, HID, 1);
    }

    kan_fused<<<2048, NTH, 0, stream>>>(nonm, mnf, ws, (float*)d_out);
}

// Round 2
// 1255.961 us; speedup vs baseline: 19.1985x; 19.1985x over previous
//
#include <hip/hip_runtime.h>

typedef _Float16 f16;
typedef __attribute__((ext_vector_type(4)))  _Float16 f16x4;
typedef __attribute__((ext_vector_type(8)))  _Float16 f16x8;
typedef __attribute__((ext_vector_type(16))) float    f32x16;

#define WT_L (8*256*256)   // halves per middle layer (d=1..8)

__device__ __forceinline__ float fexp2(float x) {
#if __has_builtin(__builtin_amdgcn_exp2f)
    return __builtin_amdgcn_exp2f(x);
#else
    return exp2f(x);
#endif
}

__device__ __forceinline__ float fast_tanh(float v) {
    // tanh(|v|) = (1-e)/(1+e), e = 2^(-2|v|*log2(e));  rcp rel-err ~8e-5, fine vs 2% budget
    float a = __builtin_fabsf(v);
    float e = fexp2(a * -2.8853900817779268f);
    float r = (1.0f - e) * __builtin_amdgcn_rcpf(1.0f + e);
    return __builtin_copysignf(r, v);
}

// ---------------- prep: middle layer w[i][o][d] fp32 -> wt[d-1][o][i] fp16 + bias0[o] ----------------
__global__ void prep_mid(const float* __restrict__ w, f16* __restrict__ wt, float* __restrict__ biasL) {
    __shared__ float red[256];
    const int i = threadIdx.x;      // input channel
    const int o = blockIdx.x;       // output channel
    float v[9];
#pragma unroll
    for (int d = 0; d < 9; d++) v[d] = w[(i*256 + o)*9 + d];
#pragma unroll
    for (int d = 1; d < 9; d++) wt[((d-1)*256 + o)*256 + i] = (f16)v[d];
    red[i] = v[0];
    __syncthreads();
#pragma unroll
    for (int s = 128; s > 0; s >>= 1) {
        if (i < s) red[i] += red[i + s];
        __syncthreads();
    }
    if (i == 0) biasL[o] = red[0];
}

// ---------------- prep: w0[i][o][d] fp32 -> w0t[(i*9+d)][o] fp32 ----------------
__global__ void prep_w0(const float* __restrict__ w0, float* __restrict__ w0t) {
    int id = blockIdx.x*256 + threadIdx.x;   // < 6912
    int i = id / 2304, rem = id % 2304;
    int o = rem / 9, d = rem % 9;
    w0t[(i*9 + d)*256 + o] = w0[id];
}

// ---------------- prep: w7[ch][d] fp32 -> w7p[ch*12+d] (16B-alignable rows) ----------------
__global__ void prep_w7(const float* __restrict__ w7, float* __restrict__ w7p) {
    int id = blockIdx.x*256 + threadIdx.x;   // < 2304
    int ch = id / 9, d = id % 9;
    w7p[ch*12 + d] = w7[id];
}

// ---------------- fused network: 128 pts/block, 4 waves, f16 MFMA ----------------
__global__ __launch_bounds__(256, 2)
void kan_mfma(const float* __restrict__ nonm, const float* __restrict__ mnf,
              const f16* __restrict__ wt, const float* __restrict__ bias,
              const float* __restrict__ w0t, const float* __restrict__ w7p,
              float* __restrict__ out)
{
    // x = tanh(h), fp16, [pt][ch] rows of 512B, XOR-swizzled 16B units: conflict-free b128 A-reads
    __shared__ __align__(16) f16 xs[128*256];   // 64 KB

    const int t    = threadIdx.x;
    const int b    = blockIdx.x;
    const int lane = t & 63;
    const int w    = t >> 6;       // wave 0..3 -> n-slice
    const int l31  = lane & 31;
    const int half = lane >> 5;
    const int nb   = w * 64;

    const float* src = (b < 512) ? mnf : nonm;
    const int p0 = ((b < 512) ? b : (b - 512)) * 128;

    // ---- layer 0: 3 -> 256, fp32 VALU (K=27, tiny) ----
    {
        const int pt = t >> 1;
        const int oh = (t & 1) * 128;
        float c0 = src[(p0 + pt)*3 + 0];
        float c1 = src[(p0 + pt)*3 + 1];
        float c2 = src[(p0 + pt)*3 + 2];
        float xx[3] = {fast_tanh(c0), fast_tanh(c1), fast_tanh(c2)};
        float bas[27];
#pragma unroll
        for (int i = 0; i < 3; i++) {
            float t0 = 1.0f, t1 = xx[i];
            bas[i*9+0] = t0; bas[i*9+1] = t1;
            float x2 = xx[i] + xx[i];
#pragma unroll
            for (int d = 2; d < 9; d++) {
                float t2 = x2*t1 - t0;
                bas[i*9+d] = t2; t0 = t1; t1 = t2;
            }
        }
#pragma unroll 1
        for (int q = 0; q < 32; q++) {
            int o = oh + q*4;
            float4 a = {0.f, 0.f, 0.f, 0.f};
#pragma unroll
            for (int k = 0; k < 27; k++) {
                float4 wv = *(const float4*)(w0t + k*256 + o);
                a.x = fmaf(bas[k], wv.x, a.x);
                a.y = fmaf(bas[k], wv.y, a.y);
                a.z = fmaf(bas[k], wv.z, a.z);
                a.w = fmaf(bas[k], wv.w, a.w);
            }
            f16x4 hv = {(f16)fast_tanh(a.x), (f16)fast_tanh(a.y),
                        (f16)fast_tanh(a.z), (f16)fast_tanh(a.w)};
            int unit = (o >> 3) ^ (pt & 7);
            *(f16x4*)(xs + pt*256 + unit*8 + (o & 7)) = hv;
        }
    }
    __syncthreads();

    // ---- layers 1..6: 256 -> 256 via 8 degree-GEMMs (d=0 folded into bias) ----
    f32x16 acc[4][2];
    const f16x8 ones = {(f16)1.f,(f16)1.f,(f16)1.f,(f16)1.f,(f16)1.f,(f16)1.f,(f16)1.f,(f16)1.f};

#pragma unroll 1
    for (int L = 0; L < 6; L++) {
        const f16* wl = wt + L*WT_L;
        float b0 = bias[L*256 + nb + l31];
        float b1 = bias[L*256 + nb + 32 + l31];
#pragma unroll
        for (int mt = 0; mt < 4; mt++)
#pragma unroll
            for (int r = 0; r < 16; r++) { acc[mt][0][r] = b0; acc[mt][1][r] = b1; }

#pragma unroll 1
        for (int ck = 0; ck < 16; ck++) {
            f16x8 x2[4], t1[4], t0[4];
#pragma unroll
            for (int mt = 0; mt < 4; mt++) {
                int m = mt*32 + l31;
                int unit = (ck*2 + half) ^ (m & 7);
                f16x8 xv = *(const f16x8*)(xs + m*256 + unit*8);
                t1[mt] = xv;
                x2[mt] = xv + xv;
                t0[mt] = ones;
            }
            const f16* wck = wl + ck*16 + half*8 + (nb + l31)*256;
#pragma unroll
            for (int d = 1; d <= 8; d++) {
                f16x8 bf0 = *(const f16x8*)(wck + (d-1)*65536);
                f16x8 bf1 = *(const f16x8*)(wck + (d-1)*65536 + 32*256);
#pragma unroll
                for (int mt = 0; mt < 4; mt++) {
                    acc[mt][0] = __builtin_amdgcn_mfma_f32_32x32x16_f16(t1[mt], bf0, acc[mt][0], 0, 0, 0);
                    acc[mt][1] = __builtin_amdgcn_mfma_f32_32x32x16_f16(t1[mt], bf1, acc[mt][1], 0, 0, 0);
                }
                if (d < 8) {
#pragma unroll
                    for (int mt = 0; mt < 4; mt++) {
                        f16x8 tn = x2[mt]*t1[mt] - t0[mt];
                        t0[mt] = t1[mt];
                        t1[mt] = tn;
                    }
                }
            }
        }
        __syncthreads();   // all xs reads for this layer done
        // writeback: x' = tanh(acc)  (tanh applied once per element)
#pragma unroll
        for (int mt = 0; mt < 4; mt++) {
#pragma unroll
            for (int nt = 0; nt < 2; nt++) {
                int ch = nb + nt*32 + l31;
                int cu = ch >> 3, ce = ch & 7;
#pragma unroll
                for (int r = 0; r < 16; r++) {
                    int p = mt*32 + (r & 3) + 8*(r >> 2) + 4*half;
                    int unit = cu ^ (p & 7);
                    xs[p*256 + unit*8 + ce] = (f16)fast_tanh(acc[mt][nt][r]);
                }
            }
        }
        __syncthreads();
    }

    // ---- layer 7: 256 -> 1, fp32 VALU ----
    {
        const int pt = t & 127;
        const int hh = t >> 7;
        float s = 0.0f;
#pragma unroll 1
        for (int q = 0; q < 16; q++) {
            int u = hh*16 + q;
            int unit = u ^ (pt & 7);
            f16x8 xv = *(const f16x8*)(xs + pt*256 + unit*8);
#pragma unroll
            for (int e = 0; e < 8; e++) {
                int ch = u*8 + e;
                float x = (float)xv[e];
                const float* wr = w7p + ch*12;
                float4 wa = *(const float4*)(wr);
                float4 wb = *(const float4*)(wr + 4);
                float wc = wr[8];
                float x2 = x + x;
                float t0 = 1.0f, t1v = x;
                s = fmaf(wa.x, t0, s);
                s = fmaf(wa.y, t1v, s);
                float t2 = x2*t1v - t0;  s = fmaf(wa.z, t2, s);
                float t3 = x2*t2 - t1v;  s = fmaf(wa.w, t3, s);
                float t4 = x2*t3 - t2;   s = fmaf(wb.x, t4, s);
                float t5 = x2*t4 - t3;   s = fmaf(wb.y, t5, s);
                float t6 = x2*t5 - t4;   s = fmaf(wb.z, t6, s);
                float t7 = x2*t6 - t5;   s = fmaf(wb.w, t7, s);
                float t8 = x2*t7 - t6;   s = fmaf(wc,  t8, s);
            }
        }
        __syncthreads();
        float* red = (float*)xs;
        red[hh*128 + pt] = s;
        __syncthreads();
        if (t < 128) out[b*128 + t] = red[t] + red[128 + t];
    }
}

// ---------------- launch ----------------
extern "C" void kernel_launch(void* const* d_in, const int* in_sizes, int n_in,
                              void* d_out, int out_size, void* d_ws, size_t ws_size,
                              hipStream_t stream) {
    const float* nonm = (const float*)d_in[0];
    const float* mnf  = (const float*)d_in[1];

    char* ws = (char*)d_ws;
    f16*   wtp   = (f16*)ws;                                   // 6*WT_L halves = 6,291,456 B
    float* biasp = (float*)(ws + 6*WT_L*2);                    // 6*256 fp32
    float* w0tp  = (float*)(ws + 6*WT_L*2 + 6*256*4);          // 27*256 fp32
    float* w7pp  = (float*)(ws + 6*WT_L*2 + 6*256*4 + 27*256*4); // 256*12 fp32

    for (int L = 0; L < 6; L++)
        prep_mid<<<256, 256, 0, stream>>>((const float*)d_in[3 + L], wtp + L*WT_L, biasp + L*256);
    prep_w0<<<27, 256, 0, stream>>>((const float*)d_in[2], w0tp);
    prep_w7<<<9, 256, 0, stream>>>((const float*)d_in[9], w7pp);

    kan_mfma<<<1024, 256, 0, stream>>>(nonm, mnf, wtp, biasp, w0tp, w7pp, (float*)d_out);
}

// Round 3
// 1250.667 us; speedup vs baseline: 19.2797x; 1.0042x over previous
//
#include <hip/hip_runtime.h>

typedef _Float16 f16;
typedef __attribute__((ext_vector_type(4)))  _Float16 f16x4;
typedef __attribute__((ext_vector_type(8)))  _Float16 f16x8;
typedef __attribute__((ext_vector_type(16))) float    f32x16;

#define WT_L (8*256*256)   // halves per middle layer (d=1..8)

__device__ __forceinline__ float fexp2(float x) {
#if __has_builtin(__builtin_amdgcn_exp2f)
    return __builtin_amdgcn_exp2f(x);
#else
    return exp2f(x);
#endif
}

__device__ __forceinline__ float fast_tanh(float v) {
    float a = __builtin_fabsf(v);
    float e = fexp2(a * -2.8853900817779268f);
    float r = (1.0f - e) * __builtin_amdgcn_rcpf(1.0f + e);
    return __builtin_copysignf(r, v);
}

// ---------------- prep: middle layer w[i][o][d] fp32 -> wt[d-1][o][i] fp16 + bias0[o] ----------------
__global__ void prep_mid(const float* __restrict__ w, f16* __restrict__ wt, float* __restrict__ biasL) {
    __shared__ float red[256];
    const int i = threadIdx.x;      // input channel
    const int o = blockIdx.x;       // output channel
    float v[9];
#pragma unroll
    for (int d = 0; d < 9; d++) v[d] = w[(i*256 + o)*9 + d];
#pragma unroll
    for (int d = 1; d < 9; d++) wt[((d-1)*256 + o)*256 + i] = (f16)v[d];
    red[i] = v[0];
    __syncthreads();
#pragma unroll
    for (int s = 128; s > 0; s >>= 1) {
        if (i < s) red[i] += red[i + s];
        __syncthreads();
    }
    if (i == 0) biasL[o] = red[0];
}

__global__ void prep_w0(const float* __restrict__ w0, float* __restrict__ w0t) {
    int id = blockIdx.x*256 + threadIdx.x;   // < 6912
    int i = id / 2304, rem = id % 2304;
    int o = rem / 9, d = rem % 9;
    w0t[(i*9 + d)*256 + o] = w0[id];
}

__global__ void prep_w7(const float* __restrict__ w7, float* __restrict__ w7p) {
    int id = blockIdx.x*256 + threadIdx.x;   // < 2304
    int ch = id / 9, d = id % 9;
    w7p[ch*12 + d] = w7[id];
}

// ---------------- fused network: 128 pts/block, 4 waves, f16 MFMA, 4-deep B pipeline ----------------
__global__ __launch_bounds__(256, 2)
void kan_mfma(const float* __restrict__ nonm, const float* __restrict__ mnf,
              const f16* __restrict__ wt, const float* __restrict__ bias,
              const float* __restrict__ w0t, const float* __restrict__ w7p,
              float* __restrict__ out)
{
    __shared__ __align__(16) f16 xs[128*256];   // 64 KB, [pt][ch], XOR-swizzled 16B units

    const int t    = threadIdx.x;
    const int b    = blockIdx.x;
    const int lane = t & 63;
    const int w    = t >> 6;
    const int l31  = lane & 31;
    const int half = lane >> 5;
    const int nb   = w * 64;

    const float* src = (b < 512) ? mnf : nonm;
    const int p0 = ((b < 512) ? b : (b - 512)) * 128;

    // ---- layer 0: 3 -> 256, fp32 VALU ----
    {
        const int pt = t >> 1;
        const int oh = (t & 1) * 128;
        float c0 = src[(p0 + pt)*3 + 0];
        float c1 = src[(p0 + pt)*3 + 1];
        float c2 = src[(p0 + pt)*3 + 2];
        float xx[3] = {fast_tanh(c0), fast_tanh(c1), fast_tanh(c2)};
        float bas[27];
#pragma unroll
        for (int i = 0; i < 3; i++) {
            float t0 = 1.0f, t1 = xx[i];
            bas[i*9+0] = t0; bas[i*9+1] = t1;
            float x2 = xx[i] + xx[i];
#pragma unroll
            for (int d = 2; d < 9; d++) {
                float t2 = x2*t1 - t0;
                bas[i*9+d] = t2; t0 = t1; t1 = t2;
            }
        }
#pragma unroll 1
        for (int q = 0; q < 32; q++) {
            int o = oh + q*4;
            float4 a = {0.f, 0.f, 0.f, 0.f};
#pragma unroll
            for (int k = 0; k < 27; k++) {
                float4 wv = *(const float4*)(w0t + k*256 + o);
                a.x = fmaf(bas[k], wv.x, a.x);
                a.y = fmaf(bas[k], wv.y, a.y);
                a.z = fmaf(bas[k], wv.z, a.z);
                a.w = fmaf(bas[k], wv.w, a.w);
            }
            f16x4 hv = {(f16)fast_tanh(a.x), (f16)fast_tanh(a.y),
                        (f16)fast_tanh(a.z), (f16)fast_tanh(a.w)};
            int unit = (o >> 3) ^ (pt & 7);
            *(f16x4*)(xs + pt*256 + unit*8 + (o & 7)) = hv;
        }
    }
    __syncthreads();

    // ---- layers 1..6: 256 -> 256, 8 degree-GEMMs, 4-slot B prefetch pipeline ----
    f32x16 acc[4][2];
    const f16x8 ones = {(f16)1.f,(f16)1.f,(f16)1.f,(f16)1.f,(f16)1.f,(f16)1.f,(f16)1.f,(f16)1.f};

#pragma unroll 1
    for (int L = 0; L < 6; L++) {
        const f16* wbase = wt + L*WT_L + half*8 + (nb + l31)*256;  // + ck*16 + j*65536 (+8192 for nt1)
        float b0 = bias[L*256 + nb + l31];
        float b1 = bias[L*256 + nb + 32 + l31];
#pragma unroll
        for (int mt = 0; mt < 4; mt++)
#pragma unroll
            for (int r = 0; r < 16; r++) { acc[mt][0][r] = b0; acc[mt][1][r] = b1; }

        // prologue: A for ck=0, B slots for steps 0..3
        f16x8 xv[4], Bb[4][2];
#pragma unroll
        for (int mt = 0; mt < 4; mt++) {
            int m = mt*32 + l31;
            int unit = half ^ (m & 7);
            xv[mt] = *(const f16x8*)(xs + m*256 + unit*8);
        }
#pragma unroll
        for (int j = 0; j < 4; j++) {
            Bb[j][0] = *(const f16x8*)(wbase + j*65536);
            Bb[j][1] = *(const f16x8*)(wbase + j*65536 + 8192);
        }

        f16x8 x2[4], t1[4], t0[4];
#pragma unroll 1
        for (int ck = 0; ck < 16; ck++) {
            const int ckn = (ck < 15) ? ck + 1 : 15;
            // build fragments for this ck, then issue A ds_reads for next ck
#pragma unroll
            for (int mt = 0; mt < 4; mt++) {
                t1[mt] = xv[mt];
                x2[mt] = xv[mt] + xv[mt];
                t0[mt] = ones;
            }
#pragma unroll
            for (int mt = 0; mt < 4; mt++) {
                int m = mt*32 + l31;
                int unit = (ckn*2 + half) ^ (m & 7);
                xv[mt] = *(const f16x8*)(xs + m*256 + unit*8);
            }
#pragma unroll
            for (int j = 0; j < 8; j++) {
                // prefetch B for step j+4 (rolls into next ck; clamped at layer end)
                const int ck2 = (j < 4) ? ck : ckn;
                const int j2  = (j < 4) ? (j + 4) : (j - 4);
                f16x8 nb0 = *(const f16x8*)(wbase + ck2*16 + j2*65536);
                f16x8 nb1 = *(const f16x8*)(wbase + ck2*16 + j2*65536 + 8192);
#pragma unroll
                for (int mt = 0; mt < 4; mt++) {
                    acc[mt][0] = __builtin_amdgcn_mfma_f32_32x32x16_f16(t1[mt], Bb[j&3][0], acc[mt][0], 0, 0, 0);
                    acc[mt][1] = __builtin_amdgcn_mfma_f32_32x32x16_f16(t1[mt], Bb[j&3][1], acc[mt][1], 0, 0, 0);
                }
                if (j < 7) {
#pragma unroll
                    for (int mt = 0; mt < 4; mt++) {
                        f16x8 tn = x2[mt]*t1[mt] - t0[mt];
                        t0[mt] = t1[mt];
                        t1[mt] = tn;
                    }
                }
                Bb[j&3][0] = nb0;
                Bb[j&3][1] = nb1;
            }
        }
        __syncthreads();   // all xs reads done
#pragma unroll
        for (int mt = 0; mt < 4; mt++) {
#pragma unroll
            for (int nt = 0; nt < 2; nt++) {
                int ch = nb + nt*32 + l31;
                int cu = ch >> 3, ce = ch & 7;
#pragma unroll
                for (int r = 0; r < 16; r++) {
                    int p = mt*32 + (r & 3) + 8*(r >> 2) + 4*half;
                    int unit = cu ^ (p & 7);
                    xs[p*256 + unit*8 + ce] = (f16)fast_tanh(acc[mt][nt][r]);
                }
            }
        }
        __syncthreads();
    }

    // ---- layer 7: 256 -> 1, fp32 VALU ----
    {
        const int pt = t & 127;
        const int hh = t >> 7;
        float s = 0.0f;
#pragma unroll 1
        for (int q = 0; q < 16; q++) {
            int u = hh*16 + q;
            int unit = u ^ (pt & 7);
            f16x8 xv = *(const f16x8*)(xs + pt*256 + unit*8);
#pragma unroll
            for (int e = 0; e < 8; e++) {
                int ch = u*8 + e;
                float x = (float)xv[e];
                const float* wr = w7p + ch*12;
                float4 wa = *(const float4*)(wr);
                float4 wb = *(const float4*)(wr + 4);
                float wc = wr[8];
                float x2 = x + x;
                float t0 = 1.0f, t1v = x;
                s = fmaf(wa.x, t0, s);
                s = fmaf(wa.y, t1v, s);
                float t2 = x2*t1v - t0;  s = fmaf(wa.z, t2, s);
                float t3 = x2*t2 - t1v;  s = fmaf(wa.w, t3, s);
                float t4 = x2*t3 - t2;   s = fmaf(wb.x, t4, s);
                float t5 = x2*t4 - t3;   s = fmaf(wb.y, t5, s);
                float t6 = x2*t5 - t4;   s = fmaf(wb.z, t6, s);
                float t7 = x2*t6 - t5;   s = fmaf(wb.w, t7, s);
                float t8 = x2*t7 - t6;   s = fmaf(wc,  t8, s);
            }
        }
        __syncthreads();
        float* red = (float*)xs;
        red[hh*128 + pt] = s;
        __syncthreads();
        if (t < 128) out[b*128 + t] = red[t] + red[128 + t];
    }
}

// ---------------- launch ----------------
extern "C" void kernel_launch(void* const* d_in, const int* in_sizes, int n_in,
                              void* d_out, int out_size, void* d_ws, size_t ws_size,
                              hipStream_t stream) {
    const float* nonm = (const float*)d_in[0];
    const float* mnf  = (const float*)d_in[1];

    char* ws = (char*)d_ws;
    f16*   wtp   = (f16*)ws;
    float* biasp = (float*)(ws + 6*WT_L*2);
    float* w0tp  = (float*)(ws + 6*WT_L*2 + 6*256*4);
    float* w7pp  = (float*)(ws + 6*WT_L*2 + 6*256*4 + 27*256*4);

    for (int L = 0; L < 6; L++)
        prep_mid<<<256, 256, 0, stream>>>((const float*)d_in[3 + L], wtp + L*WT_L, biasp + L*256);
    prep_w0<<<27, 256, 0, stream>>>((const float*)d_in[2], w0tp);
    prep_w7<<<9, 256, 0, stream>>>((const float*)d_in[9], w7pp);

    kan_mfma<<<1024, 256, 0, stream>>>(nonm, mnf, wtp, biasp, w0tp, w7pp, (float*)d_out);
}